// Round 12
// baseline (58.748 us; speedup 1.0000x reference)
//
#include <hip/hip_runtime.h>

#define HOLE_P 0.05f
#define TW 64          // tile width
#define TH 64          // tile height
#define HALO 8
#define PRW 88         // padded row: 3 pad + guard + 80 content + guard + 3 pad
#define PRH 82         // guard + 80 content rows + guard
#define PLN 7216       // PRW*PRH
#define PWORDS 1804
#define QCAP 1536      // worklist capacity (expected ~440, ~27 sigma margin)
#define NTILES 4       // tiles per block (software pipeline depth)
#define NBLK 1024      // k_fill grid size (4096 tiles / NTILES)

// Kernel 1: pack invalid = (hole_u < p) into bitmask, 8 px per byte, flat [c][y][x/8]
__global__ void k_mask(const float* __restrict__ hole_u, unsigned char* __restrict__ inv_mask) {
    int t = blockIdx.x * blockDim.x + threadIdx.x;    // 0 .. 2M-1
    const float* base = hole_u + (size_t)t * 8;
    float4 a = *reinterpret_cast<const float4*>(base);
    float4 b = *reinterpret_cast<const float4*>(base + 4);
    unsigned int m = (a.x < HOLE_P ? 1u : 0u)  | (a.y < HOLE_P ? 2u : 0u)  |
                     (a.z < HOLE_P ? 4u : 0u)  | (a.w < HOLE_P ? 8u : 0u)  |
                     (b.x < HOLE_P ? 16u : 0u) | (b.y < HOLE_P ? 32u : 0u) |
                     (b.z < HOLE_P ? 64u : 0u) | (b.w < HOLE_P ? 128u : 0u);
    inv_mask[t] = (unsigned char)m;
}

// Kernel 2: u_small[i][j] = OR over channels of invalid[c][2i][2j]
__global__ void k_us(const unsigned char* __restrict__ inv_mask, unsigned char* __restrict__ u_small) {
    int t = blockIdx.x * blockDim.x + threadIdx.x;    // 0 .. 65535
    int i  = t >> 7;
    int jb = t & 127;
    const unsigned char* p = inv_mask + (i << 8) + jb;
    unsigned int b = 0;
#pragma unroll
    for (int c = 0; c < 16; ++c) b |= p[c * 131072];
    unsigned int o = (b & 1u) | (((b >> 2) & 1u) << 8) | (((b >> 4) & 1u) << 16) | (((b >> 6) & 1u) << 24);
    *reinterpret_cast<unsigned int*>(u_small + i * 512 + jb * 4) = o;
}

// Kernel 3: d_small = cross-dilate(u_small), zero pad
__global__ void k_dil(const unsigned char* __restrict__ u_small, unsigned char* __restrict__ d_small) {
    int g = blockIdx.x * blockDim.x + threadIdx.x;
    int i = g >> 9, j = g & 511;
    unsigned char d = u_small[g];
    if (i > 0)   d |= u_small[g - 512];
    if (i < 511) d |= u_small[g + 512];
    if (j > 0)   d |= u_small[g - 1];
    if (j < 511) d |= u_small[g + 1];
    d_small[g] = d;
}

// Halo group index h (0..575) -> (row 0..79, col-group 0..19) of 80x80 content.
__device__ __forceinline__ void halo_map(int h, int& ly, int& lxg) {
    if (h < 160)      { ly = h / 20;                lxg = h - (h / 20) * 20; }
    else if (h < 320) { int t2 = h - 160; ly = 72 + t2 / 20; lxg = t2 - (t2 / 20) * 20; }
    else              { int t2 = h - 320; ly = 8 + (t2 >> 2); int q = t2 & 3; lxg = q < 2 ? q : q + 16; }
}

// State-word encode from src/invalid nibbles (bit i -> byte i).
__device__ __forceinline__ unsigned int enc_w(unsigned int src, unsigned int nib) {
    return ((src * 0x204081u) & 0x01010101u) | (((nib * 0x204081u) & 0x01010101u) << 7);
}

// Per-tile prefetched state (2 register sets alternate under full unroll).
struct TR {
    float4 xx0, xx1, axx, bxx;
    unsigned int mb0, mb1, amb, bmb;
    unsigned int dsA, dsB, ads, bds;
    int by0, bx0;                 // uniform
    const float* xc;              // uniform
    float* oc;                    // uniform
    bool ain, bin, cornerTile;
};

// Issue ALL global loads for one tile (no LDS access; safe to run pre-barrier).
__device__ __forceinline__ void tile_load(
    const float* __restrict__ x, const unsigned char* __restrict__ inv_mask,
    const unsigned char* __restrict__ d_small, float* __restrict__ out,
    int tileId, int r0, int cg0, int aly, int alxg, int bly, int blxg, bool hasB,
    TR& R)
{
    int c  = tileId >> 8;
    int ty = (tileId >> 4) & 15;
    int tx = tileId & 15;
    R.by0 = ty * TH; R.bx0 = tx * TW;
    R.xc = x + c * 1048576;
    R.oc = out + c * 1048576;
    const unsigned char* mc = inv_mask + c * 131072;
    R.cornerTile = ((tx == 0) | (tx == 15)) & ((ty == 0) | (ty == 15));
    int gy0 = R.by0 + r0, gx0 = R.bx0 + cg0 * 4;
    int gy1 = gy0 + 32;
    R.xx0 = *reinterpret_cast<const float4*>(R.xc + gy0 * 1024 + gx0);
    R.xx1 = *reinterpret_cast<const float4*>(R.xc + gy1 * 1024 + gx0);
    R.mb0 = mc[(gy0 << 7) + (gx0 >> 3)];
    R.mb1 = mc[(gy1 << 7) + (gx0 >> 3)];
    R.dsA = *reinterpret_cast<const unsigned short*>(d_small + ((gy0 >> 1) << 9) + (gx0 >> 1));
    R.dsB = *reinterpret_cast<const unsigned short*>(d_small + ((gy1 >> 1) << 9) + (gx0 >> 1));
    int agy = R.by0 - HALO + aly, agx0 = R.bx0 - HALO + alxg * 4;
    int bgy = R.by0 - HALO + bly, bgx0 = R.bx0 - HALO + blxg * 4;
    R.ain = ((unsigned)agy < 1024u) & ((unsigned)agx0 < 1024u);
    R.bin = hasB & ((unsigned)bgy < 1024u) & ((unsigned)bgx0 < 1024u);
    R.axx = make_float4(0.f, 0.f, 0.f, 0.f); R.bxx = R.axx;
    R.amb = 0; R.bmb = 0; R.ads = 0; R.bds = 0;
    if (R.ain) {
        int gi = agy * 1024 + agx0;
        R.axx = *reinterpret_cast<const float4*>(R.xc + gi);
        R.amb = mc[(agy << 7) + (agx0 >> 3)];
        R.ads = *reinterpret_cast<const unsigned short*>(d_small + ((agy >> 1) << 9) + (agx0 >> 1));
    }
    if (R.bin) {
        int gi = bgy * 1024 + bgx0;
        R.bxx = *reinterpret_cast<const float4*>(R.xc + gi);
        R.bmb = mc[(bgy << 7) + (bgx0 >> 3)];
        R.bds = *reinterpret_cast<const unsigned short*>(d_small + ((bgy >> 1) << 9) + (bgx0 >> 1));
    }
}

// Kernel 4: 64x64 tiles, halo 8, guard-ring padded LDS. Each block runs 4
// tiles sequentially; tile t+1's global loads are issued right after tile t's
// encode (its loads are dead), so they fly during tile t's Jacobi+epilogue.
// w byte: bit7 = invalid; low7: 0 = fillable, 1 = source, it+2 = filled at it,
// 0x7f = guard/out-of-image. Worklist Jacobi (1 px/lane), monotone states,
// pending-interior + stationary exits, dense-sweep fallback on q overflow.
__global__ __launch_bounds__(512, 4) void k_fill(
    const float* __restrict__ x, const unsigned char* __restrict__ inv_mask,
    const unsigned char* __restrict__ d_small, float* __restrict__ out)
{
    __shared__ __align__(16) float v[PLN];
    __shared__ unsigned int w32[PWORDS];
    __shared__ unsigned short q[QCAP];
    __shared__ int qn;
    __shared__ int chgf[8], pendf[8];
    unsigned char* w = (unsigned char*)w32;

    const int tid = threadIdx.x;
    const int lane = tid & 63;
    const int r0  = tid >> 4, cg0 = tid & 15;
    int aly, alxg, bly, blxg;
    halo_map(tid, aly, alxg);
    const bool hasB = (tid < 64);
    halo_map(hasB ? tid + 512 : 0, bly, blxg);
    const int P0i0 = (9 + r0) * PRW + 12 + cg0 * 4;
    const int P0i1 = P0i0 + 32 * PRW;
    const int P0A  = (aly + 1) * PRW + 4 + alxg * 4;
    const int P0B  = (bly + 1) * PRW + 4 + blxg * 4;

    // guard ring + pads = 0x7f sentinel (constant across tiles: init once)
    if (tid < 204) {
        int wi;
        if (tid < 22)      wi = tid;                         // top row (row 0)
        else if (tid < 44) wi = 81 * 22 + (tid - 22);        // bottom row (row 81)
        else {                                               // rows 1..80, left/right word
            int r = ((tid - 44) >> 1) + 1;
            wi = r * 22 + (((tid - 44) & 1) ? 21 : 0);
        }
        w32[wi] = 0x7f7f7f7fu;
    }
    if (tid < 8) { chgf[tid] = 0; pendf[tid] = 0; }
    if (tid == 0) qn = 0;

    TR R[2];
    tile_load(x, inv_mask, d_small, out, blockIdx.x,
              r0, cg0, aly, alxg, bly, blxg, hasB, R[0]);
    __syncthreads();                      // guards + resets visible

#pragma unroll
    for (int t = 0; t < NTILES; ++t) {
        TR& C = R[t & 1];

        // ---- encode + LDS writes; collect fillable/invalid nibbles ----
        unsigned int fN0, fN1, fNA = 0, fNB = 0;
        unsigned int iN0, iN1, iNA = 0, iNB = 0;
        int gx0 = C.bx0 + cg0 * 4;
        {
            int gy0 = C.by0 + r0;
            unsigned int nib = (C.mb0 >> (gx0 & 7)) & 0xfu;
            unsigned int db = ((C.dsA & 0xffu) ? 0x3u : 0u) | ((C.dsA & 0xff00u) ? 0xcu : 0u);
            unsigned int src = db & ~nib & 0xfu;
            if (C.cornerTile && ((gy0 == 0) | (gy0 == 1023)))
                src |= (gx0 == 0 ? 1u : 0u) | (gx0 == 1020 ? 8u : 0u);
            unsigned int vs = src & ~nib;
            float4 vv;
            vv.x = (vs & 1u) ? C.xx0.x : 0.0f;
            vv.y = (vs & 2u) ? C.xx0.y : 0.0f;
            vv.z = (vs & 4u) ? C.xx0.z : 0.0f;
            vv.w = (vs & 8u) ? C.xx0.w : 0.0f;
            *reinterpret_cast<float4*>(&v[P0i0]) = vv;
            w32[P0i0 >> 2] = enc_w(src, nib);
            fN0 = ~src & 0xfu; iN0 = nib;
        }
        {
            int gy1 = C.by0 + r0 + 32;
            unsigned int nib = (C.mb1 >> (gx0 & 7)) & 0xfu;
            unsigned int db = ((C.dsB & 0xffu) ? 0x3u : 0u) | ((C.dsB & 0xff00u) ? 0xcu : 0u);
            unsigned int src = db & ~nib & 0xfu;
            if (C.cornerTile && ((gy1 == 0) | (gy1 == 1023)))
                src |= (gx0 == 0 ? 1u : 0u) | (gx0 == 1020 ? 8u : 0u);
            unsigned int vs = src & ~nib;
            float4 vv;
            vv.x = (vs & 1u) ? C.xx1.x : 0.0f;
            vv.y = (vs & 2u) ? C.xx1.y : 0.0f;
            vv.z = (vs & 4u) ? C.xx1.z : 0.0f;
            vv.w = (vs & 8u) ? C.xx1.w : 0.0f;
            *reinterpret_cast<float4*>(&v[P0i1]) = vv;
            w32[P0i1 >> 2] = enc_w(src, nib);
            fN1 = ~src & 0xfu; iN1 = nib;
        }
        {   // halo A (all threads)
            int agx0 = C.bx0 - HALO + alxg * 4;
            float4 vv = make_float4(0.f, 0.f, 0.f, 0.f);
            unsigned int ww = 0x7f7f7f7fu;
            if (C.ain) {
                unsigned int nib = (C.amb >> (agx0 & 7)) & 0xfu;
                unsigned int db = ((C.ads & 0xffu) ? 0x3u : 0u) | ((C.ads & 0xff00u) ? 0xcu : 0u);
                unsigned int src = db & ~nib & 0xfu;     // corners never in halo
                ww = enc_w(src, nib);
                vv.x = (src & 1u) ? C.axx.x : 0.0f;
                vv.y = (src & 2u) ? C.axx.y : 0.0f;
                vv.z = (src & 4u) ? C.axx.z : 0.0f;
                vv.w = (src & 8u) ? C.axx.w : 0.0f;
                fNA = ~src & 0xfu; iNA = nib;
            }
            *reinterpret_cast<float4*>(&v[P0A]) = vv;
            w32[P0A >> 2] = ww;
        }
        if (hasB) {   // halo B (tid < 64)
            int bgx0 = C.bx0 - HALO + blxg * 4;
            float4 vv = make_float4(0.f, 0.f, 0.f, 0.f);
            unsigned int ww = 0x7f7f7f7fu;
            if (C.bin) {
                unsigned int nib = (C.bmb >> (bgx0 & 7)) & 0xfu;
                unsigned int db = ((C.bds & 0xffu) ? 0x3u : 0u) | ((C.bds & 0xff00u) ? 0xcu : 0u);
                unsigned int src = db & ~nib & 0xfu;
                ww = enc_w(src, nib);
                vv.x = (src & 1u) ? C.bxx.x : 0.0f;
                vv.y = (src & 2u) ? C.bxx.y : 0.0f;
                vv.z = (src & 4u) ? C.bxx.z : 0.0f;
                vv.w = (src & 8u) ? C.bxx.w : 0.0f;
                fNB = ~src & 0xfu; iNB = nib;
            }
            *reinterpret_cast<float4*>(&v[P0B]) = vv;
            w32[P0B >> 2] = ww;
        }

        // ---- prefetch next tile (loads fly during Jacobi + epilogue) ----
        if (t + 1 < NTILES)
            tile_load(x, inv_mask, d_small, out, (t + 1) * NBLK + blockIdx.x,
                      r0, cg0, aly, alxg, bly, blxg, hasB, R[(t + 1) & 1]);

        // ---- wave-compacted worklist build (prefix-sum + 1 atomic/wave) ----
        int cnt = __popc(fN0) + __popc(fN1) + __popc(fNA) + __popc(fNB);
        int xsum = cnt;
#pragma unroll
        for (int d = 1; d < 64; d <<= 1) {
            int y = __shfl_up(xsum, d, 64);
            if (lane >= d) xsum += y;
        }
        int base = 0;
        if (lane == 63) base = atomicAdd(&qn, xsum);
        base = __shfl(base, 63, 64);
        int idx = base + (xsum - cnt);
#define PUSH(m_, iv_, pd_, gp_) { unsigned int m = (m_); while (m) {            \
        int b = __builtin_ctz(m); m &= m - 1;                                   \
        unsigned int e = (unsigned int)((gp_) + b) | ((((iv_) >> b) & 1u) << 14)\
                         | ((((pd_) >> b) & 1u) << 15);                         \
        if (idx < QCAP) q[idx] = (unsigned short)e; ++idx; } }
        PUSH(fN0, iN0, fN0 & iN0, P0i0)    // interior: pend = fillable & invalid
        PUSH(fN1, iN1, fN1 & iN1, P0i1)
        PUSH(fNA, iNA, 0u, P0A)            // halo: never pend-relevant
        PUSH(fNB, iNB, 0u, P0B)
#undef PUSH
        __syncthreads();                   // encode + q visible; qn final

        const int n = qn;
        if (n <= QCAP) {
            // ---- worklist Jacobi: 1 px/lane; skip filled via state byte ----
            for (int it = 0; it < 8; ++it) {
                int chg = 0, pend = 0;
                unsigned int thr = (unsigned int)it;
                for (int i = tid; i < n; i += 512) {
                    unsigned int e = q[i];
                    int p = e & 0x1fffu;
                    if (w[p] & 0x7fu) continue;            // already filled
                    unsigned int qu = w[p - PRW] & 0x7fu;
                    unsigned int qd = w[p + PRW] & 0x7fu;
                    unsigned int ql = w[p - 1]   & 0x7fu;
                    unsigned int qr = w[p + 1]   & 0x7fu;
                    bool su = (qu - 1u) <= thr, sd = (qd - 1u) <= thr;
                    bool sl = (ql - 1u) <= thr, sr = (qr - 1u) <= thr;
                    float s = (su ? v[p - PRW] : 0.0f) + (sd ? v[p + PRW] : 0.0f)
                            + (sl ? v[p - 1]   : 0.0f) + (sr ? v[p + 1]   : 0.0f);
                    int cn = (int)su + (int)sd + (int)sl + (int)sr;
                    if (cn > 0) {
                        v[p] = s / (float)cn;              // reads gated by old states
                        w[p] = (unsigned char)((((e >> 14) & 1u) << 7) | (unsigned int)(it + 2));
                        chg = 1;
                    } else {
                        pend |= (int)((e >> 15) & 1u);
                    }
                }
                if (chg)  chgf[it] = 1;                    // benign all-write-1 races
                if (pend) pendf[it] = 1;
                __syncthreads();
                if (chgf[it] == 0 || pendf[it] == 0) break;
            }
        } else {
            // ---- overflow fallback (~never): dense sweeps over all words ----
            for (int it = 0; it < 8; ++it) {
                int chg = 0;
                unsigned int thr = (unsigned int)it;
                for (int wp = tid; wp < PWORDS; wp += 512) {
                    unsigned int cw = w32[wp];
                    unsigned int st = cw & 0x7f7f7f7fu;
                    if ((((st - 0x01010101u) & ~st) & 0x80808080u) == 0u) continue;
                    int p0 = wp * 4;
#pragma unroll
                    for (int b = 0; b < 4; ++b) {
                        if (((st >> (8 * b)) & 0x7fu) != 0u) continue;  // exact per-byte
                        int p = p0 + b;
                        unsigned int qu = w[p - PRW] & 0x7fu, qd = w[p + PRW] & 0x7fu;
                        unsigned int ql = w[p - 1] & 0x7fu,   qr = w[p + 1] & 0x7fu;
                        bool su = (qu - 1u) <= thr, sd = (qd - 1u) <= thr;
                        bool sl = (ql - 1u) <= thr, sr = (qr - 1u) <= thr;
                        float s = (su ? v[p - PRW] : 0.0f) + (sd ? v[p + PRW] : 0.0f)
                                + (sl ? v[p - 1]   : 0.0f) + (sr ? v[p + 1]   : 0.0f);
                        int cn = (int)su + (int)sd + (int)sl + (int)sr;
                        if (cn > 0) {
                            v[p] = s / (float)cn;
                            w[p] = (unsigned char)(((cw >> (8 * b)) & 0x80u) | (unsigned int)(it + 2));
                            chg = 1;
                        }
                    }
                }
                if (chg) chgf[it] = 1;
                __syncthreads();
                if (chgf[it] == 0) break;
            }
        }
        // (both Jacobi exits pass through a __syncthreads: w/v stable here)

        // ---- epilogue: blended coalesced store, out = invalid ? v : x_reg ----
#pragma unroll
        for (int k = 0; k < 2; ++k) {
            int r  = r0 + k * 32;
            int p0 = (9 + r) * PRW + 12 + cg0 * 4;
            unsigned int cw = w32[p0 >> 2];
            float4 vv = *reinterpret_cast<const float4*>(&v[p0]);
            float4 xx = (k == 0) ? C.xx0 : C.xx1;
            float4 o;
            o.x = (cw & 0x00000080u) ? vv.x : xx.x;
            o.y = (cw & 0x00008000u) ? vv.y : xx.y;
            o.z = (cw & 0x00800000u) ? vv.z : xx.z;
            o.w = (cw & 0x80000000u) ? vv.w : xx.w;
            *reinterpret_cast<float4*>(C.oc + (C.by0 + r) * 1024 + C.bx0 + cg0 * 4) = o;
        }

        // ---- prep next tile: reset flags (flag reads were pre-barrier) ----
        if (t + 1 < NTILES) {
            if (tid < 8) { chgf[tid] = 0; pendf[tid] = 0; }
            if (tid == 0) qn = 0;
            __syncthreads();   // epilogue w/v reads done before next encode writes
        }
    }
}

extern "C" void kernel_launch(void* const* d_in, const int* in_sizes, int n_in,
                              void* d_out, int out_size, void* d_ws, size_t ws_size,
                              hipStream_t stream) {
    (void)in_sizes; (void)n_in; (void)out_size; (void)ws_size;
    const float* x      = (const float*)d_in[0];
    const float* hole_u = (const float*)d_in[1];
    float* out = (float*)d_out;
    unsigned char* u_small  = (unsigned char*)d_ws;           // 256 KiB
    unsigned char* d_small  = u_small + 262144;               // 256 KiB
    unsigned char* inv_mask = d_small + 262144;               // 2 MiB

    k_mask<<<8192, 256, 0, stream>>>(hole_u, inv_mask);       // 2M threads, 8 px each
    k_us  <<<256, 256, 0, stream>>>(inv_mask, u_small);
    k_dil <<<1024, 256, 0, stream>>>(u_small, d_small);
    k_fill<<<NBLK, 512, 0, stream>>>(x, inv_mask, d_small, out);
}